// Round 6
// baseline (458.082 us; speedup 1.0000x reference)
//
#include <hip/hip_runtime.h>
#include <stdint.h>

// WL refinement step: hash rows -> tile-sorted edge binning (LDS counting-sort
// per 8K-edge tile, PACKED u64 stage, wave-shfl scan, coalesced flush) ->
// per-bucket LDS multiset accumulation (single commutative u64 sum,
// srcpart-windowed lab gathers) with fused node-hash + hash-table insert ->
// probe-free lookup -> first-appearance contiguous relabel.
//
// R6 changes (post-mortem of R5): neither wave-count (R1: occ 2x -> -6%) nor
// ILP (R5: VGPR=36 proves compiler never held 16 gathers) moves k_accum ->
// it is bound by per-CU serialized memory-path ops (~1 cy/lane TA divergent
// gather + u64 LDS atomic). Scatter (est ~140us, ideal 33us) is LDS-pipe +
// barrier bound (5 LDS ops/edge + 20-barrier scan/tile). So: cut ops/edge.
//  * scatter: stage ONE packed u64 (resolved addr<<32 | rec) instead of
//    rec+cell (5 -> 3 LDS ops/edge); wave-shfl scan (20 -> 2 barriers);
//    TILE 8192 so the 64KB packed stage fits.
//  * accum: revert R5's per-sp barriers + mega-unroll (the regression);
//    keep all-lanes-active xp-groups, simple 4-record chunks.

#define KC1 6364136223846793005ULL
#define KC2 1442695040888963407ULL
#define KC3 2862933555777941757ULL
#define KC4 3202034522624059733ULL
#define KPT 1000003ULL

#define TBL_BITS 21
#define TBL (1u << TBL_BITS)
#define TMASK (TBL - 1u)
#define KEMPTY 0xFFFFFFFFFFFFFFFFULL
#define SIGMASK 0xFFFFFFFFFFF00000ULL   // high 44 bits = signature, low 20 = node idx

// binning: 4096 nodes per bucket (dl=12 bits, src=20 bits -> 32-bit record)
#define BK_SHIFT 12
#define BK_NODES 4096
#define NBK_MAX 256
// 8 block-partitions (blockIdx&7, write privacy) x 4 src-range partitions
// (accum gather window = 2MB of lab). cell = (bk << 2) | sp.
#define NPARTX 8
#define NPARTS 4
#define NPARTS_LOG 2
// per (part,cell) capacity: n=2M p=1/980 -> mean 2041, sigma ~45; ~4K total
// spills expected -> exact ovf path (verified absmax=0 in R3/R4/R5).
#define PCAP 2132u
#define OVFCAP 32768u

// scatter tile: 8192 records staged in LDS as packed u64, 8 recs/thread
#define TILE 8192
#define SUBP 2           // sub-passes of 4096 records (1024 thr x 4)

typedef int iv4 __attribute__((ext_vector_type(4)));

__device__ __forceinline__ uint64_t mix64(uint64_t h, uint64_t a, uint64_t b) {
    h *= a;
    h ^= (uint64_t)(((int64_t)h) >> 31);   // arithmetic shift, like jnp int64
    h *= b;
    h ^= (uint64_t)(((int64_t)h) >> 29);
    return h;
}

__device__ __forceinline__ uint32_t tslot(uint64_t k) {
    return (uint32_t)((k * 0x9E3779B97F4A7C15ULL) >> (64 - TBL_BITS));
}

// src-partition via magic-mul division: p = (src * M) >> 38, clamped.
__device__ __forceinline__ uint32_t psel(uint32_t src, uint32_t M) {
    uint32_t p = (uint32_t)(((uint64_t)src * (uint64_t)M) >> 38);
    return p < (NPARTS - 1) ? p : (NPARTS - 1);
}

// 1. lab[i] = mix(poly(x[i,:]), C1, C2)
__global__ void k_lab(const int* __restrict__ x, uint64_t* __restrict__ lab, int N, int F) {
    int i = blockIdx.x * blockDim.x + threadIdx.x;
    if (i >= N) return;
    const int* row = x + (size_t)i * (size_t)F;
    uint64_t l = 0;
    for (int j = 0; j < F; ++j) l = l * KPT + (uint64_t)(int64_t)row[j];
    lab[i] = mix64(l, KC1, KC2);
}

// 2a. tile-sorted binning. Per 8K-edge tile: LDS hist -> wave-shfl scan ->
//     per-cell global reservation -> PACKED (addr,rec) stage -> coalesced
//     flush. Requires ncl = NPARTS*NBK <= 1024 (true for N <= 1,048,576).
__global__ __launch_bounds__(1024)
void k_scatter(const int* __restrict__ ei, uint32_t* __restrict__ binned,
               uint32_t* __restrict__ cursor, unsigned long long* __restrict__ ovf,
               unsigned int* __restrict__ ovf_cnt, int E, int NBK, int chunk,
               uint32_t M) {
    __shared__ unsigned long long stagePk[TILE];        // 64 KB (addr32|rec32)
    __shared__ uint32_t hist[NPARTS * NBK_MAX];         // 4 KB
    __shared__ uint32_t cstart[NPARTS * NBK_MAX];       // 4 KB
    __shared__ uint32_t lbrun[NPARTS * NBK_MAX];        // 4 KB
    __shared__ uint32_t wsum[16];                       // -> ~76 KB total
    const int ncl = NPARTS * NBK;                       // 980; <= 1024 required
    const int part = blockIdx.x & (NPARTX - 1);
    const int tid = threadIdx.x;
    const int lane = tid & 63;
    const int wid = tid >> 6;
    const size_t partBase = (size_t)part * ncl * PCAP;
    const int b0 = blockIdx.x * chunk;
    const int b1 = min(E, b0 + chunk);
    if (b0 >= b1) return;

    if (tid < ncl) hist[tid] = 0;
    __syncthreads();

    for (int tb = b0; tb < b1; tb += TILE) {
        const int tE = min(TILE, b1 - tb);
        const int lim = min(b1, tb + TILE);
        // ---- 1. load up to 8 edges/thread, count cells.
        //         meta = (cell<<13)|pos (cell<980 -> 10b, pos<8192 -> 13b).
        uint32_t rc[SUBP * 4];
        uint32_t meta[SUBP * 4];
#pragma unroll
        for (int sidx = 0; sidx < SUBP; ++sidx) {
            const int base = tb + sidx * 4096 + tid * 4;
            int ss[4], dd[4];
            int m = 0;
            if (base + 4 <= lim) {
                iv4 s4 = __builtin_nontemporal_load((const iv4*)(ei + base));
                iv4 d4 = __builtin_nontemporal_load((const iv4*)(ei + (size_t)E + base));
                ss[0]=s4.x; ss[1]=s4.y; ss[2]=s4.z; ss[3]=s4.w;
                dd[0]=d4.x; dd[1]=d4.y; dd[2]=d4.z; dd[3]=d4.w;
                m = 4;
            } else {
                int r = lim - base;
                m = r > 0 ? (r < 4 ? r : 4) : 0;
                for (int j = 0; j < m; ++j) {
                    ss[j] = ei[base + j];
                    dd[j] = ei[(size_t)E + base + j];
                }
            }
#pragma unroll
            for (int j = 0; j < 4; ++j) {
                const int k = sidx * 4 + j;
                if (j < m) {
                    uint32_t bk = (uint32_t)dd[j] >> BK_SHIFT;
                    uint32_t cell = (bk << NPARTS_LOG) | psel((uint32_t)ss[j], M);
                    uint32_t pos = atomicAdd(&hist[cell], 1u);
                    rc[k] = ((uint32_t)(dd[j] & (BK_NODES - 1)) << 20) | (uint32_t)ss[j];
                    meta[k] = (cell << 13) | pos;
                } else {
                    meta[k] = 0xFFFFFFFFu;
                }
            }
        }
        __syncthreads();
        // ---- 2. wave-shfl exclusive scan of hist (2 barriers, not 20)
        uint32_t v = (tid < ncl) ? hist[tid] : 0u;
        uint32_t s = v;
#pragma unroll
        for (int off = 1; off < 64; off <<= 1) {
            uint32_t t = __shfl_up(s, off, 64);
            if (lane >= off) s += t;
        }
        if (lane == 63) wsum[wid] = s;
        __syncthreads();
        if (wid == 0) {
            uint32_t w = (lane < 16) ? wsum[lane] : 0u;
#pragma unroll
            for (int off = 1; off < 16; off <<= 1) {
                uint32_t t = __shfl_up(w, off, 64);
                if (lane >= off) w += t;
            }
            if (lane < 16) wsum[lane] = w;
        }
        __syncthreads();
        uint32_t incl = s + ((wid > 0) ? wsum[wid - 1] : 0u);
        // ---- 3. exclusive fixup + per-cell global reservation
        if (tid < ncl) {
            cstart[tid] = incl - v;
            lbrun[tid] = v ? atomicAdd(&cursor[part * ncl + tid], v) : 0u;
        }
        __syncthreads();
        // ---- 4. stage packed (addr,rec), resolving overflow here
#pragma unroll
        for (int k = 0; k < SUBP * 4; ++k) {
            if (meta[k] != 0xFFFFFFFFu) {
                uint32_t cell = meta[k] >> 13;
                uint32_t pos  = meta[k] & 0x1FFFu;
                uint32_t idx = lbrun[cell] + pos;
                uint32_t p = cstart[cell] + pos;
                if (idx < PCAP) {
                    stagePk[p] = ((unsigned long long)(cell * PCAP + idx) << 32) | rc[k];
                } else {
                    unsigned int o = atomicAdd(ovf_cnt, 1u);
                    if (o < OVFCAP)
                        ovf[o] = ((unsigned long long)(cell >> NPARTS_LOG) << 32) | rc[k];
                    stagePk[p] = 0xFFFFFFFF00000000ULL | rc[k];   // skip marker
                }
            }
        }
        __syncthreads();
        // ---- 5. coalesced flush (lane-adjacent i -> contiguous per-cell runs)
        for (int i = tid; i < tE; i += 1024) {
            unsigned long long pk = stagePk[i];
            uint32_t addr = (uint32_t)(pk >> 32);
            if (addr != 0xFFFFFFFFu)
                binned[partBase + addr] = (uint32_t)pk;
        }
        if (tid < ncl) hist[tid] = 0;   // ready for next tile
        __syncthreads();
    }
}

// helper: accumulate one record into s1
__device__ __forceinline__ void acc_rec(unsigned long long* s1,
                                        const uint64_t* __restrict__ lab,
                                        uint32_t rec) {
    uint64_t nl = lab[rec & 0xFFFFFu];
    atomicAdd(&s1[rec >> 20], (unsigned long long)mix64(nl, KC1, KC2));
}

// 2b. per-bucket LDS multiset accumulation; sp-outer loop keeps the lab
//     gather window 2MB (L2-resident). ONE u64 LDS atomic/edge. 8 thread-
//     groups of 128 cover the 8 xp segments (all lanes active); NO intra-
//     phase barriers (R4 was faster without; windows overlap <= 2 sp = 4MB).
__global__ __launch_bounds__(1024)
void k_accum(const uint32_t* __restrict__ binned, const uint32_t* __restrict__ cursor,
             const unsigned long long* __restrict__ ovf, const unsigned int* __restrict__ ovf_cnt,
             const uint64_t* __restrict__ lab, unsigned long long* __restrict__ table,
             uint32_t* __restrict__ slot32, int N, int NBK) {
    __shared__ unsigned long long s1[BK_NODES];
    const int ncl = NPARTS * NBK;
    int b = blockIdx.x;
    for (int t = threadIdx.x; t < BK_NODES; t += blockDim.x) s1[t] = 0ULL;
    __syncthreads();
    const int xp = threadIdx.x >> 7;          // segment group (0..7)
    const int lt = threadIdx.x & 127;         // lane within group
    for (int sp = 0; sp < NPARTS; ++sp) {
        const uint32_t cell = ((uint32_t)b << NPARTS_LOG) | (uint32_t)sp;
        const size_t cidx = (size_t)xp * ncl + cell;
        uint32_t cnt = cursor[cidx];
        if (cnt > PCAP) cnt = PCAP;
        const uint32_t* seg = binned + cidx * PCAP;
#pragma unroll 2
        for (uint32_t i = (uint32_t)lt * 4u; i < cnt; i += 512u) {
            if (i + 4u <= cnt) {
                iv4 r4 = __builtin_nontemporal_load((const iv4*)(seg + i));
                acc_rec(s1, lab, (uint32_t)r4.x);
                acc_rec(s1, lab, (uint32_t)r4.y);
                acc_rec(s1, lab, (uint32_t)r4.z);
                acc_rec(s1, lab, (uint32_t)r4.w);
            } else {
                for (uint32_t j = i; j < cnt; ++j) acc_rec(s1, lab, seg[j]);
            }
        }
    }
    // overflow sweep (expected ~4K records total; exact correctness backstop)
    uint32_t oc = *ovf_cnt;
    if (oc > OVFCAP) oc = OVFCAP;
    for (uint32_t i = threadIdx.x; i < oc; i += blockDim.x) {
        unsigned long long r = ovf[i];
        if ((uint32_t)(r >> 32) == (uint32_t)b) acc_rec(s1, lab, (uint32_t)r);
    }
    __syncthreads();
    int node0 = b << BK_SHIFT;
    for (int t = threadIdx.x; t < BK_NODES; t += blockDim.x) {
        int node = node0 + t;
        if (node < N) {
            uint64_t l = lab[node];
            uint64_t s = (uint64_t)s1[t];
            // commutative-multiset combine; induces the reference partition
            uint64_t h = mix64(l * KC3 + s, KC1, KC2) ^ mix64(s + l, KC3, KC4);
            // ---- fused insert: claim slot or min-merge into same-sig slot
            uint64_t entry = (h & SIGMASK) | (uint64_t)(uint32_t)node;
            uint32_t slot = tslot(h);
            for (;;) {
                unsigned long long cur = table[slot];
                if (cur == KEMPTY) {
                    unsigned long long prev =
                        atomicCAS(&table[slot], KEMPTY, (unsigned long long)entry);
                    if (prev == KEMPTY) break;
                    cur = prev;   // lost race: resolve with the true value
                }
                if ((cur & SIGMASK) == (entry & SIGMASK)) {
                    atomicMin(&table[slot], (unsigned long long)entry);
                    break;
                }
                slot = (slot + 1u) & TMASK;
            }
            slot32[node] = slot;
        }
    }
}

// 4b+4c fused: probe-free lookup (my memoized slot holds my group's min idx),
//     flag = (rep==i), wave shfl scan + 16-wave LDS combine (2 barriers).
__global__ __launch_bounds__(1024)
void k_lookup_scan(const uint32_t* __restrict__ slot32, const unsigned long long* __restrict__ table,
                   unsigned int* __restrict__ rep, int* __restrict__ incl,
                   int* __restrict__ bsums, int N) {
    __shared__ int wsum[16];
    int tid = threadIdx.x;
    int lane = tid & 63;
    int wid = tid >> 6;
    int i = blockIdx.x * 1024 + tid;
    int v = 0;
    if (i < N) {
        unsigned long long e = table[slot32[i]];
        unsigned int r = (unsigned int)(e & 0xFFFFFu);
        rep[i] = r;
        v = (r == (unsigned int)i) ? 1 : 0;
    }
    int s = v;
#pragma unroll
    for (int off = 1; off < 64; off <<= 1) {
        int t = __shfl_up(s, off, 64);
        if (lane >= off) s += t;
    }
    if (lane == 63) wsum[wid] = s;
    __syncthreads();
    if (wid == 0) {
        int w = (lane < 16) ? wsum[lane] : 0;
#pragma unroll
        for (int off = 1; off < 16; off <<= 1) {
            int t = __shfl_up(w, off, 64);
            if (lane >= off) w += t;
        }
        if (lane < 16) wsum[lane] = w;   // inclusive scan of wave sums
    }
    __syncthreads();
    int inclv = s + ((wid > 0) ? wsum[wid - 1] : 0);
    if (i < N) incl[i] = inclv;
    if (tid == 1023) bsums[blockIdx.x] = inclv;
}

// 4d. exclusive scan of block sums (NB <= 1024, single block)
__global__ void k_scan2(const int* __restrict__ bsums, int* __restrict__ boffs, int NB) {
    __shared__ int sm[1024];
    int tid = threadIdx.x;
    int v = (tid < NB) ? bsums[tid] : 0;
    sm[tid] = v;
    __syncthreads();
    for (int off = 1; off < 1024; off <<= 1) {
        int t = (tid >= off) ? sm[tid - off] : 0;
        __syncthreads();
        sm[tid] += t;
        __syncthreads();
    }
    if (tid < NB) boffs[tid] = sm[tid] - v;  // exclusive
}

// 5. out[i] = exclusive-prefix-of-flags at rep[i]
__global__ void k_final(const unsigned int* __restrict__ rep, const int* __restrict__ incl,
                        const int* __restrict__ boffs, int* __restrict__ out, int N) {
    int i = blockIdx.x * blockDim.x + threadIdx.x;
    if (i >= N) return;
    unsigned int r = rep[i];
    out[i] = incl[r] + boffs[r >> 10] - 1;
}

extern "C" void kernel_launch(void* const* d_in, const int* in_sizes, int n_in,
                              void* d_out, int out_size, void* d_ws, size_t ws_size,
                              hipStream_t stream) {
    const int* x  = (const int*)d_in[0];
    const int* ei = (const int*)d_in[1];
    int N = out_size;
    int F = in_sizes[0] / N;
    int E = in_sizes[1] / 2;
    int* out = (int*)d_out;

    int NBK = (N + BK_NODES - 1) >> BK_SHIFT;  // 245 for N=1e6
    uint32_t PSZ = (uint32_t)((N + NPARTS - 1) / NPARTS);         // 250000
    uint32_t M = (uint32_t)(((1ULL << 38) + PSZ - 1) / PSZ);      // magic for /PSZ

    // workspace layout; ~95.93 MB total (<= 96.05 MB proven)
    char* w = (char*)d_ws;
    uint64_t* lab = (uint64_t*)w;                        w += (size_t)N * 8;       // 8 MB
    uint32_t* slot32 = (uint32_t*)w;                     w += (size_t)N * 4;       // 4 MB
    uint32_t* cursor = (uint32_t*)w;                     w += (size_t)NPARTX * NPARTS * NBK_MAX * 4; // 32 KB
    unsigned int* ovf_cnt = (unsigned int*)w;            w += 16;
    unsigned long long* ovf = (unsigned long long*)w;    w += (size_t)OVFCAP * 8;  // 256 KB
    unsigned long long* table = (unsigned long long*)w;  w += (size_t)TBL * 8;     // 16 MB (live thru lookup)
    uint32_t* binned = (uint32_t*)w;                     // 8*980*PCAP*4 (~66.9 MB)
    // rep/incl/bsums/boffs dead until after k_accum -> alias the binned region
    char* a = (char*)binned;
    unsigned int* rep = (unsigned int*)a;                a += (size_t)N * 4;
    int* incl = (int*)a;                                 a += (size_t)N * 4;
    int* bsums = (int*)a;                                a += 1024 * 4;
    int* boffs = (int*)a;                                a += 1024 * 4;

    int nb = (N + 255) / 256;
    int NB = (N + 1023) / 1024;
    int SCB = 256;                                // 1 block/CU, part = blockIdx&7
    int chunk = ((E + SCB - 1) / SCB + 3) & ~3;   // 62500 for E=16M

    (void)hipMemsetAsync(cursor, 0, (size_t)NPARTX * NPARTS * NBK_MAX * 4 + 16, stream);
    (void)hipMemsetAsync(table, 0xFF, (size_t)TBL * 8, stream);
    k_lab<<<nb, 256, 0, stream>>>(x, lab, N, F);
    k_scatter<<<SCB, 1024, 0, stream>>>(ei, binned, cursor, ovf, ovf_cnt, E, NBK, chunk, M);
    k_accum<<<NBK, 1024, 0, stream>>>(binned, cursor, ovf, ovf_cnt, lab, table, slot32, N, NBK);
    k_lookup_scan<<<NB, 1024, 0, stream>>>(slot32, table, rep, incl, bsums, N);
    k_scan2<<<1, 1024, 0, stream>>>(bsums, boffs, NB);
    k_final<<<nb, 256, 0, stream>>>(rep, incl, boffs, out, N);
}

// Round 7
// 405.129 us; speedup vs baseline: 1.1307x; 1.1307x over previous
//
#include <hip/hip_runtime.h>
#include <stdint.h>

// WL refinement step: hash rows -> tile-sorted edge binning (LDS counting-sort
// per 16K-edge tile, wave-shfl scan, coalesced flush) -> per-bucket LDS
// multiset accumulation (single commutative u64 sum, srcpart-windowed lab
// gathers) with fused node-hash + hash-table insert -> probe-free lookup ->
// first-appearance contiguous relabel. int64 arithmetic wraps (JAX).
//
// R7 = consolidation round (post-mortem R5/R6):
//  * k_accum: occupancy x2 (R1), ILP x4 (R5), lane-activity x2 (R6) all
//    moved it <= +-8% -> limiter is the per-CU outstanding-miss (MSHR) wall
//    on the lab gather (every gather L1-misses; ~64 MSHR x ~300cy L2 lat
//    => ~130us floor). R4's variant (152us) was fastest -> EXACT revert.
//  * k_scatter: R6's packed-u64 stage + TILE 8192 regressed ~35us -> revert
//    to R4's structure (TILE 16384, u32 rec + u16 cell stage), but KEEP the
//    wave-shfl scan (2 barriers vs 20 per scan; ~6 barriers/tile total).
//  * k_lab: vectorize the 8-int row read as 2x int4 (G13).

#define KC1 6364136223846793005ULL
#define KC2 1442695040888963407ULL
#define KC3 2862933555777941757ULL
#define KC4 3202034522624059733ULL
#define KPT 1000003ULL

#define TBL_BITS 21
#define TBL (1u << TBL_BITS)
#define TMASK (TBL - 1u)
#define KEMPTY 0xFFFFFFFFFFFFFFFFULL
#define SIGMASK 0xFFFFFFFFFFF00000ULL   // high 44 bits = signature, low 20 = node idx

// binning: 4096 nodes per bucket (dl=12 bits, src=20 bits -> 32-bit record)
#define BK_SHIFT 12
#define BK_NODES 4096
#define NBK_MAX 256
// 8 block-partitions (blockIdx&7, write privacy) x 4 src-range partitions
// (accum gather window = 2MB of lab). cell = (bk << 2) | sp.
#define NPARTX 8
#define NPARTS 4
#define NPARTS_LOG 2
// per (part,cell) capacity: n=2M p=1/980 -> mean 2041, sigma ~45; ~4K total
// spills expected -> exact ovf path (verified absmax=0 in R3..R6).
#define PCAP 2132u
#define OVFCAP 32768u

// scatter tile: 16384 records staged in LDS, 16 records/thread in registers
#define TILE 16384
#define SUBP 4           // sub-passes of 4096 records (1024 thr x 4)

typedef int iv4 __attribute__((ext_vector_type(4)));

__device__ __forceinline__ uint64_t mix64(uint64_t h, uint64_t a, uint64_t b) {
    h *= a;
    h ^= (uint64_t)(((int64_t)h) >> 31);   // arithmetic shift, like jnp int64
    h *= b;
    h ^= (uint64_t)(((int64_t)h) >> 29);
    return h;
}

__device__ __forceinline__ uint32_t tslot(uint64_t k) {
    return (uint32_t)((k * 0x9E3779B97F4A7C15ULL) >> (64 - TBL_BITS));
}

// src-partition via magic-mul division: p = (src * M) >> 38, clamped.
__device__ __forceinline__ uint32_t psel(uint32_t src, uint32_t M) {
    uint32_t p = (uint32_t)(((uint64_t)src * (uint64_t)M) >> 38);
    return p < (NPARTS - 1) ? p : (NPARTS - 1);
}

// 1. lab[i] = mix(poly(x[i,:]), C1, C2); row read as 2x int4
__global__ void k_lab(const int* __restrict__ x, uint64_t* __restrict__ lab, int N, int F) {
    int i = blockIdx.x * blockDim.x + threadIdx.x;
    if (i >= N) return;
    uint64_t l = 0;
    if (F == 8) {
        const iv4* p = (const iv4*)(x + (size_t)i * 8);
        iv4 a = p[0], b = p[1];
        l = (uint64_t)(int64_t)a.x;
        l = l * KPT + (uint64_t)(int64_t)a.y;
        l = l * KPT + (uint64_t)(int64_t)a.z;
        l = l * KPT + (uint64_t)(int64_t)a.w;
        l = l * KPT + (uint64_t)(int64_t)b.x;
        l = l * KPT + (uint64_t)(int64_t)b.y;
        l = l * KPT + (uint64_t)(int64_t)b.z;
        l = l * KPT + (uint64_t)(int64_t)b.w;
    } else {
        const int* row = x + (size_t)i * (size_t)F;
        for (int j = 0; j < F; ++j) l = l * KPT + (uint64_t)(int64_t)row[j];
    }
    lab[i] = mix64(l, KC1, KC2);
}

// 2a. tile-sorted binning. Per 16K-edge tile: LDS hist -> wave-shfl scan ->
//     per-cell global reservation -> cell-sorted LDS stage -> coalesced
//     flush. Requires ncl = NPARTS*NBK <= 1024 (true for N <= 1,048,576).
__global__ __launch_bounds__(1024)
void k_scatter(const int* __restrict__ ei, uint32_t* __restrict__ binned,
               uint32_t* __restrict__ cursor, unsigned long long* __restrict__ ovf,
               unsigned int* __restrict__ ovf_cnt, int E, int NBK, int chunk,
               uint32_t M) {
    __shared__ uint32_t stageRec[TILE];                 // 64 KB
    __shared__ unsigned short stageCell[TILE];          // 32 KB
    __shared__ uint32_t hist[NPARTS * NBK_MAX];         // 4 KB
    __shared__ uint32_t cstart[NPARTS * NBK_MAX];       // 4 KB
    __shared__ uint32_t lbrun[NPARTS * NBK_MAX];        // 4 KB
    __shared__ uint32_t wsum[16];                       // -> ~108 KB total
    const int ncl = NPARTS * NBK;                       // 980; <= 1024 required
    const int part = blockIdx.x & (NPARTX - 1);
    const int tid = threadIdx.x;
    const int lane = tid & 63;
    const int wid = tid >> 6;
    const int b0 = blockIdx.x * chunk;
    const int b1 = min(E, b0 + chunk);
    if (b0 >= b1) return;

    if (tid < ncl) hist[tid] = 0;
    __syncthreads();

    for (int tb = b0; tb < b1; tb += TILE) {
        const int tE = min(TILE, b1 - tb);
        const int lim = min(b1, tb + TILE);
        // ---- 1. load up to 16 edges/thread (compile-time reg indices),
        //         count cells. meta = (cell<<14)|pos, sentinel ~0u.
        uint32_t rc[SUBP * 4];
        uint32_t meta[SUBP * 4];
#pragma unroll
        for (int sidx = 0; sidx < SUBP; ++sidx) {
            const int base = tb + sidx * 4096 + tid * 4;
            int ss[4], dd[4];
            int m = 0;
            if (base + 4 <= lim) {
                iv4 s4 = __builtin_nontemporal_load((const iv4*)(ei + base));
                iv4 d4 = __builtin_nontemporal_load((const iv4*)(ei + (size_t)E + base));
                ss[0]=s4.x; ss[1]=s4.y; ss[2]=s4.z; ss[3]=s4.w;
                dd[0]=d4.x; dd[1]=d4.y; dd[2]=d4.z; dd[3]=d4.w;
                m = 4;
            } else {
                int r = lim - base;
                m = r > 0 ? (r < 4 ? r : 4) : 0;
                for (int j = 0; j < m; ++j) {
                    ss[j] = ei[base + j];
                    dd[j] = ei[(size_t)E + base + j];
                }
            }
#pragma unroll
            for (int j = 0; j < 4; ++j) {
                const int k = sidx * 4 + j;
                if (j < m) {
                    uint32_t bk = (uint32_t)dd[j] >> BK_SHIFT;
                    uint32_t cell = (bk << NPARTS_LOG) | psel((uint32_t)ss[j], M);
                    uint32_t pos = atomicAdd(&hist[cell], 1u);
                    rc[k] = ((uint32_t)(dd[j] & (BK_NODES - 1)) << 20) | (uint32_t)ss[j];
                    meta[k] = (cell << 14) | pos;      // pos < 16384
                } else {
                    meta[k] = 0xFFFFFFFFu;
                }
            }
        }
        __syncthreads();
        // ---- 2. wave-shfl exclusive scan of hist (2 barriers, not 20)
        uint32_t v = (tid < ncl) ? hist[tid] : 0u;
        uint32_t s = v;
#pragma unroll
        for (int off = 1; off < 64; off <<= 1) {
            uint32_t t = __shfl_up(s, off, 64);
            if (lane >= off) s += t;
        }
        if (lane == 63) wsum[wid] = s;
        __syncthreads();
        if (wid == 0) {
            uint32_t w = (lane < 16) ? wsum[lane] : 0u;
#pragma unroll
            for (int off = 1; off < 16; off <<= 1) {
                uint32_t t = __shfl_up(w, off, 64);
                if (lane >= off) w += t;
            }
            if (lane < 16) wsum[lane] = w;   // inclusive scan of wave sums
        }
        __syncthreads();
        uint32_t incl = s + ((wid > 0) ? wsum[wid - 1] : 0u);
        // ---- 3. exclusive fixup + per-cell global reservation
        if (tid < ncl) {
            cstart[tid] = incl - v;
            lbrun[tid] = v ? atomicAdd(&cursor[part * ncl + tid], v) : 0u;
        }
        __syncthreads();
        // ---- 4. stage records sorted by cell
#pragma unroll
        for (int k = 0; k < SUBP * 4; ++k) {
            if (meta[k] != 0xFFFFFFFFu) {
                uint32_t cell = meta[k] >> 14;
                uint32_t p = cstart[cell] + (meta[k] & 0x3FFFu);
                stageRec[p] = rc[k];
                stageCell[p] = (unsigned short)cell;
            }
        }
        __syncthreads();
        // ---- 5. coalesced flush (lane-adjacent i -> contiguous per-cell runs)
        for (int i = tid; i < tE; i += 1024) {
            uint32_t rec = stageRec[i];
            uint32_t c = stageCell[i];
            uint32_t idx = lbrun[c] + ((uint32_t)i - cstart[c]);
            if (idx < PCAP) {
                binned[((size_t)part * ncl + c) * PCAP + idx] = rec;
            } else {
                unsigned int o = atomicAdd(ovf_cnt, 1u);
                if (o < OVFCAP) ovf[o] = ((unsigned long long)(c >> NPARTS_LOG) << 32) | rec;
            }
        }
        if (tid < ncl) hist[tid] = 0;   // ready for next tile
        __syncthreads();
    }
}

// 2b. per-bucket LDS multiset accumulation; sp-outer loop keeps the lab
//     gather window 2MB (L2-resident). ONE u64 LDS atomic/edge. EXACT R4
//     structure (fastest measured: 152us; MSHR-wall-bound, do not touch).
__global__ __launch_bounds__(1024)
void k_accum(const uint32_t* __restrict__ binned, const uint32_t* __restrict__ cursor,
             const unsigned long long* __restrict__ ovf, const unsigned int* __restrict__ ovf_cnt,
             const uint64_t* __restrict__ lab, unsigned long long* __restrict__ table,
             uint32_t* __restrict__ slot32, int N, int NBK) {
    __shared__ unsigned long long s1[BK_NODES];
    const int ncl = NPARTS * NBK;
    int b = blockIdx.x;
    for (int t = threadIdx.x; t < BK_NODES; t += blockDim.x) s1[t] = 0ULL;
    __syncthreads();
    for (int sp = 0; sp < NPARTS; ++sp) {
        const uint32_t cell = ((uint32_t)b << NPARTS_LOG) | (uint32_t)sp;
        for (int xp = 0; xp < NPARTX; ++xp) {
            size_t cidx = (size_t)xp * ncl + cell;
            uint32_t cnt = cursor[cidx];
            if (cnt > PCAP) cnt = PCAP;
            const uint32_t* seg = binned + cidx * PCAP;
            for (uint32_t i = threadIdx.x * 4; i < cnt; i += blockDim.x * 4) {
                uint32_t recs[4];
                int m;
                if (i + 4 <= cnt) {
                    iv4 r4 = __builtin_nontemporal_load((const iv4*)(seg + i));
                    recs[0]=(uint32_t)r4.x; recs[1]=(uint32_t)r4.y;
                    recs[2]=(uint32_t)r4.z; recs[3]=(uint32_t)r4.w;
                    m = 4;
                } else {
                    m = (int)(cnt - i);
                    for (int j = 0; j < m; ++j) recs[j] = seg[i + j];
                }
                for (int j = 0; j < m; ++j) {
                    uint64_t nl = lab[recs[j] & 0xFFFFFu];
                    uint32_t dl = recs[j] >> 20;
                    atomicAdd(&s1[dl], (unsigned long long)mix64(nl, KC1, KC2));
                }
            }
        }
    }
    // overflow sweep (expected ~4K records total; exact correctness backstop)
    uint32_t oc = *ovf_cnt;
    if (oc > OVFCAP) oc = OVFCAP;
    for (uint32_t i = threadIdx.x; i < oc; i += blockDim.x) {
        unsigned long long r = ovf[i];
        if ((uint32_t)(r >> 32) == (uint32_t)b) {
            uint32_t rec = (uint32_t)r;
            uint64_t nl = lab[rec & 0xFFFFFu];
            uint32_t dl = rec >> 20;
            atomicAdd(&s1[dl], (unsigned long long)mix64(nl, KC1, KC2));
        }
    }
    __syncthreads();
    int node0 = b << BK_SHIFT;
    for (int t = threadIdx.x; t < BK_NODES; t += blockDim.x) {
        int node = node0 + t;
        if (node < N) {
            uint64_t l = lab[node];
            uint64_t s = (uint64_t)s1[t];
            // commutative-multiset combine; induces the reference partition
            uint64_t h = mix64(l * KC3 + s, KC1, KC2) ^ mix64(s + l, KC3, KC4);
            // ---- fused insert: claim slot or min-merge into same-sig slot
            uint64_t entry = (h & SIGMASK) | (uint64_t)(uint32_t)node;
            uint32_t slot = tslot(h);
            for (;;) {
                unsigned long long cur = table[slot];
                if (cur == KEMPTY) {
                    unsigned long long prev =
                        atomicCAS(&table[slot], KEMPTY, (unsigned long long)entry);
                    if (prev == KEMPTY) break;
                    cur = prev;   // lost race: resolve with the true value
                }
                if ((cur & SIGMASK) == (entry & SIGMASK)) {
                    atomicMin(&table[slot], (unsigned long long)entry);
                    break;
                }
                slot = (slot + 1u) & TMASK;
            }
            slot32[node] = slot;
        }
    }
}

// 4b+4c fused: probe-free lookup (my memoized slot holds my group's min idx),
//     flag = (rep==i), wave shfl scan + 16-wave LDS combine (2 barriers).
__global__ __launch_bounds__(1024)
void k_lookup_scan(const uint32_t* __restrict__ slot32, const unsigned long long* __restrict__ table,
                   unsigned int* __restrict__ rep, int* __restrict__ incl,
                   int* __restrict__ bsums, int N) {
    __shared__ int wsum[16];
    int tid = threadIdx.x;
    int lane = tid & 63;
    int wid = tid >> 6;
    int i = blockIdx.x * 1024 + tid;
    int v = 0;
    if (i < N) {
        unsigned long long e = table[slot32[i]];
        unsigned int r = (unsigned int)(e & 0xFFFFFu);
        rep[i] = r;
        v = (r == (unsigned int)i) ? 1 : 0;
    }
    int s = v;
#pragma unroll
    for (int off = 1; off < 64; off <<= 1) {
        int t = __shfl_up(s, off, 64);
        if (lane >= off) s += t;
    }
    if (lane == 63) wsum[wid] = s;
    __syncthreads();
    if (wid == 0) {
        int w = (lane < 16) ? wsum[lane] : 0;
#pragma unroll
        for (int off = 1; off < 16; off <<= 1) {
            int t = __shfl_up(w, off, 64);
            if (lane >= off) w += t;
        }
        if (lane < 16) wsum[lane] = w;   // inclusive scan of wave sums
    }
    __syncthreads();
    int inclv = s + ((wid > 0) ? wsum[wid - 1] : 0);
    if (i < N) incl[i] = inclv;
    if (tid == 1023) bsums[blockIdx.x] = inclv;
}

// 4d. exclusive scan of block sums (NB <= 1024, single block)
__global__ void k_scan2(const int* __restrict__ bsums, int* __restrict__ boffs, int NB) {
    __shared__ int sm[1024];
    int tid = threadIdx.x;
    int v = (tid < NB) ? bsums[tid] : 0;
    sm[tid] = v;
    __syncthreads();
    for (int off = 1; off < 1024; off <<= 1) {
        int t = (tid >= off) ? sm[tid - off] : 0;
        __syncthreads();
        sm[tid] += t;
        __syncthreads();
    }
    if (tid < NB) boffs[tid] = sm[tid] - v;  // exclusive
}

// 5. out[i] = exclusive-prefix-of-flags at rep[i]
__global__ void k_final(const unsigned int* __restrict__ rep, const int* __restrict__ incl,
                        const int* __restrict__ boffs, int* __restrict__ out, int N) {
    int i = blockIdx.x * blockDim.x + threadIdx.x;
    if (i >= N) return;
    unsigned int r = rep[i];
    out[i] = incl[r] + boffs[r >> 10] - 1;
}

extern "C" void kernel_launch(void* const* d_in, const int* in_sizes, int n_in,
                              void* d_out, int out_size, void* d_ws, size_t ws_size,
                              hipStream_t stream) {
    const int* x  = (const int*)d_in[0];
    const int* ei = (const int*)d_in[1];
    int N = out_size;
    int F = in_sizes[0] / N;
    int E = in_sizes[1] / 2;
    int* out = (int*)d_out;

    int NBK = (N + BK_NODES - 1) >> BK_SHIFT;  // 245 for N=1e6
    uint32_t PSZ = (uint32_t)((N + NPARTS - 1) / NPARTS);         // 250000
    uint32_t M = (uint32_t)(((1ULL << 38) + PSZ - 1) / PSZ);      // magic for /PSZ

    // workspace layout; ~95.93 MB total (<= 96.05 MB proven)
    char* w = (char*)d_ws;
    uint64_t* lab = (uint64_t*)w;                        w += (size_t)N * 8;       // 8 MB
    uint32_t* slot32 = (uint32_t*)w;                     w += (size_t)N * 4;       // 4 MB
    uint32_t* cursor = (uint32_t*)w;                     w += (size_t)NPARTX * NPARTS * NBK_MAX * 4; // 32 KB
    unsigned int* ovf_cnt = (unsigned int*)w;            w += 16;
    unsigned long long* ovf = (unsigned long long*)w;    w += (size_t)OVFCAP * 8;  // 256 KB
    unsigned long long* table = (unsigned long long*)w;  w += (size_t)TBL * 8;     // 16 MB (live thru lookup)
    uint32_t* binned = (uint32_t*)w;                     // 8*980*PCAP*4 (~66.9 MB)
    // rep/incl/bsums/boffs dead until after k_accum -> alias the binned region
    char* a = (char*)binned;
    unsigned int* rep = (unsigned int*)a;                a += (size_t)N * 4;
    int* incl = (int*)a;                                 a += (size_t)N * 4;
    int* bsums = (int*)a;                                a += 1024 * 4;
    int* boffs = (int*)a;                                a += 1024 * 4;

    int nb = (N + 255) / 256;
    int NB = (N + 1023) / 1024;
    int SCB = 256;                                // 1 block/CU, part = blockIdx&7
    int chunk = ((E + SCB - 1) / SCB + 3) & ~3;   // 62500 for E=16M

    (void)hipMemsetAsync(cursor, 0, (size_t)NPARTX * NPARTS * NBK_MAX * 4 + 16, stream);
    (void)hipMemsetAsync(table, 0xFF, (size_t)TBL * 8, stream);
    k_lab<<<nb, 256, 0, stream>>>(x, lab, N, F);
    k_scatter<<<SCB, 1024, 0, stream>>>(ei, binned, cursor, ovf, ovf_cnt, E, NBK, chunk, M);
    k_accum<<<NBK, 1024, 0, stream>>>(binned, cursor, ovf, ovf_cnt, lab, table, slot32, N, NBK);
    k_lookup_scan<<<NB, 1024, 0, stream>>>(slot32, table, rep, incl, bsums, N);
    k_scan2<<<1, 1024, 0, stream>>>(bsums, boffs, NB);
    k_final<<<nb, 256, 0, stream>>>(rep, incl, boffs, out, N);
}